// Round 3
// baseline (1072.816 us; speedup 1.0000x reference)
//
#include <hip/hip_runtime.h>

#define CDIM 128
#define HDIM 64

typedef float v2f __attribute__((ext_vector_type(2)));

__device__ __forceinline__ float rdl(float v, int l) {
    return __uint_as_float(__builtin_amdgcn_readlane(__float_as_uint(v), (unsigned)l));
}

// acc.x += xs.x*wv.x; acc.y += xs.y*wv.y — one VOP3P instr, 2 MACs/lane.
// xs is wave-uniform (readlane results land in SGPRs); "s" makes it the single
// scalar operand of the VOP3P, wv/acc are VGPR pairs. 2x FLOP/instr vs v_fmac.
__device__ __forceinline__ void pk_fma(v2f& acc, v2f xs, v2f wv) {
    asm("v_pk_fma_f32 %0, %1, %2, %0" : "+v"(acc) : "s"(xs), "v"(wv));
}

__device__ __forceinline__ float fast_tanh(float v) {
    // tanh(v) = 1 - 2/(1+exp(2v)); exp via exp2. Saturates correctly:
    // v>>0: e=inf -> rcp=0 -> 1 ; v<<0: e=0 -> 1-2 = -1.
    float e = __builtin_amdgcn_exp2f(v * 2.88539008177792681f); // 2*log2(e)
    return 1.0f - 2.0f * __builtin_amdgcn_rcpf(1.0f + e);
}

__global__ __launch_bounds__(256, 3)
void attn_pc_kernel(const float* __restrict__ x1, const float* __restrict__ x2,
                    const float* __restrict__ W1, const float* __restrict__ b1,
                    const float* __restrict__ W2, const float* __restrict__ b2,
                    float* __restrict__ out, int nrows) {
    const int lane  = threadIdx.x & 63;
    const int wave  = blockIdx.x * (blockDim.x >> 6) + (threadIdx.x >> 6);
    const int nwave = gridDim.x * (blockDim.x >> 6);

    // W1 column `lane` resident as 64 float2 pairs (128 VGPRs), loaded once:
    // wp[t] = { W1[2t][lane], W1[2t+1][lane] }  (W1 is [C=128][H=64] row-major)
    v2f wp[HDIM];
#pragma unroll
    for (int t = 0; t < HDIM; ++t) {
        v2f w; w.x = W1[(2 * t) * HDIM + lane]; w.y = W1[(2 * t + 1) * HDIM + lane];
        wp[t] = w;
    }
    const float vb1 = b1[lane];
    const float vw2 = W2[lane];
    const float sb2 = b2[0];

    // Output tuple layout: Z [N,1,2C] flat, then beta [N,2,1] flat.
    float* outZ = out;
    float* outB = out + (size_t)nrows * (2 * CDIM);

    // One wave per row. lanes 0..31 carry x1[row][4*sub..4*sub+3] (float4),
    // lanes 32..63 carry x2[row][...] — the row is loaded exactly once and
    // retained in registers for both the GEMV (via readlane) and the epilogue.
    const int half = lane >> 5;
    const int sub  = lane & 31;
    const float* xbase = half ? x2 : x1;

    int row = wave;
    if (row >= nrows) return;

    float4 cur = *(reinterpret_cast<const float4*>(xbase + (size_t)row * CDIM) + sub);

    for (; row < nrows; row += nwave) {
        // prefetch next row's quad (clamped addr; value unused on last iter)
        int nrow = row + nwave;
        int srow = (nrow < nrows) ? nrow : row;
        float4 nxt = *(reinterpret_cast<const float4*>(xbase + (size_t)srow * CDIM) + sub);

        const float c0 = cur.x, c1 = cur.y, c2 = cur.z, c3 = cur.w;

        // two accumulator chains per score to break FMA latency chains
        v2f H1a, H1b, H2a, H2b;
        H1a.x = vb1; H1a.y = 0.0f; H1b.x = 0.0f; H1b.y = 0.0f;
        H2a.x = vb1; H2a.y = 0.0f; H2b.x = 0.0f; H2b.y = 0.0f;

#pragma unroll
        for (int kq = 0; kq < 32; ++kq) {
            // x1[row][4kq+i] lives in lane kq comp i; x2 in lane 32+kq
            float a0 = rdl(c0, kq),      a1 = rdl(c1, kq);
            float a2 = rdl(c2, kq),      a3 = rdl(c3, kq);
            float e0 = rdl(c0, 32 + kq), e1 = rdl(c1, 32 + kq);
            float e2 = rdl(c2, 32 + kq), e3 = rdl(c3, 32 + kq);
            v2f xa01; xa01.x = a0; xa01.y = a1;
            v2f xa23; xa23.x = a2; xa23.y = a3;
            v2f xe01; xe01.x = e0; xe01.y = e1;
            v2f xe23; xe23.x = e2; xe23.y = e3;
            pk_fma(H1a, xa01, wp[2 * kq]);
            pk_fma(H1b, xa23, wp[2 * kq + 1]);
            pk_fma(H2a, xe01, wp[2 * kq]);
            pk_fma(H2b, xe23, wp[2 * kq + 1]);
        }
        const float h1 = (H1a.x + H1b.x) + (H1a.y + H1b.y);
        const float h2 = (H2a.x + H2b.x) + (H2a.y + H2b.y);

        // leaky_relu(0.01) == max(x, 0.01x); dot with W2[lane] across 64 lanes
        float s1 = fmaxf(h1, 0.01f * h1) * vw2;
        float s2 = fmaxf(h2, 0.01f * h2) * vw2;
#pragma unroll
        for (int off = 32; off; off >>= 1) {
            s1 += __shfl_xor(s1, off, 64);
            s2 += __shfl_xor(s2, off, 64);
        }
        const float w1s = s1 + sb2;
        const float w2s = s2 + sb2;

        // softmax over 2: beta1 = 1/(1+e^{w2-w1}), beta2 = 1-beta1
        float e  = __builtin_amdgcn_exp2f((w2s - w1s) * 1.44269504088896341f);
        float r  = __builtin_amdgcn_rcpf(1.0f + e);
        float beta1 = r;
        float beta2 = e * r;

        // epilogue: z = tanh(beta * x); x still in registers
        const float bsel = half ? beta2 : beta1;
        float4 zq;
        zq.x = fast_tanh(bsel * c0);
        zq.y = fast_tanh(bsel * c1);
        zq.z = fast_tanh(bsel * c2);
        zq.w = fast_tanh(bsel * c3);

        // Z[row][half*128 + 4*sub .. +3]: one fully coalesced 1KB store per wave
        *(reinterpret_cast<float4*>(outZ + (size_t)row * (2 * CDIM) + half * CDIM) + sub) = zq;

        if (lane == 0) {
            float2 bb; bb.x = beta1; bb.y = beta2;
            *reinterpret_cast<float2*>(outB + (size_t)row * 2) = bb;
        }
        cur = nxt;
    }
}

extern "C" void kernel_launch(void* const* d_in, const int* in_sizes, int n_in,
                              void* d_out, int out_size, void* d_ws, size_t ws_size,
                              hipStream_t stream) {
    const float* x1 = (const float*)d_in[0];
    const float* x2 = (const float*)d_in[1];
    const float* W1 = (const float*)d_in[2];
    const float* b1 = (const float*)d_in[3];
    const float* W2 = (const float*)d_in[4];
    const float* b2 = (const float*)d_in[5];
    float* out = (float*)d_out;
    const int nrows = in_sizes[0] / CDIM;

    // 768 blocks x 256 threads = 3072 waves = exactly resident at 3 waves/SIMD
    // (launch_bounds-pinned); each wave strides ~163 rows.
    dim3 grid(768), block(256);
    hipLaunchKernelGGL(attn_pc_kernel, grid, block, 0, stream,
                       x1, x2, W1, b1, W2, b2, out, nrows);
}